// Round 3
// baseline (1403.160 us; speedup 1.0000x reference)
//
#include <hip/hip_runtime.h>

// VQ-MoE: per-token nearest-code search + straight-through z_q + loss.
// R3: fp32 tiled GEMM-argmin main pass + near-tie rescue that EMULATES the
// numpy-fp32 reference semantics: d32 = fl32(fl32(zsum32+csum32) - fl32(2*dot)),
// argmin first-index tie-break. The +||z||^2 constant makes the reference's
// fp32 ulp ~2e-5, so near-tie tokens TIE in the reference and it picks the
// lower index -- which exact math cannot reproduce. Emulation can.

#define TM 64
#define TN 64
#define BK 32
#define LDSTR 68
#define EPS_GAP 2e-3f

// ---------------- csum: per-code ||c||^2, fp64 + fp32 views ----------------
__global__ __launch_bounds__(256) void csum_kernel(
    const float* __restrict__ cb0, const float* __restrict__ cb1,
    const float* __restrict__ cb2, const float* __restrict__ cb3,
    float* __restrict__ csums, double* __restrict__ csums64) {
  int row = blockIdx.x * 4 + (threadIdx.x >> 6);   // one wave per row
  int lane = threadIdx.x & 63;
  const float* src; int r;
  if (row < 256)       { src = cb0; r = row; }
  else if (row < 768)  { src = cb1; r = row - 256; }
  else if (row < 1792) { src = cb2; r = row - 768; }
  else                 { src = cb3; r = row - 1792; }
  float4 v = ((const float4*)(src + r * 256))[lane];
  double s = (double)v.x*v.x + (double)v.y*v.y + (double)v.z*v.z + (double)v.w*v.w;
  #pragma unroll
  for (int off = 32; off >= 1; off >>= 1) s += __shfl_down(s, off, 64);
  if (lane == 0) { csums[row] = (float)s; csums64[row] = s; }
}

// ---------------- zsq: sum of all z^2 (fp64 partials) ----------------
__global__ __launch_bounds__(256) void zsq_kernel(const float* __restrict__ z,
                                                  double* __restrict__ parts) {
  const float4* p = (const float4*)z;
  const int n4 = 4194304;  // 64*1024*256/4
  double s = 0.0;
  for (int i = blockIdx.x * 256 + threadIdx.x; i < n4; i += 256 * 256) {
    float4 v = p[i];
    s += (double)v.x*(double)v.x + (double)v.y*(double)v.y
       + (double)v.z*(double)v.z + (double)v.w*(double)v.w;
  }
  #pragma unroll
  for (int off = 32; off >= 1; off >>= 1) s += __shfl_down(s, off, 64);
  __shared__ double sh[4];
  if ((threadIdx.x & 63) == 0) sh[threadIdx.x >> 6] = s;
  __syncthreads();
  if (threadIdx.x == 0) parts[blockIdx.x] = sh[0] + sh[1] + sh[2] + sh[3];
}

// ---------------- main: distances + argmin(+2nd) + z_q + loss partials ----------------
__global__ __launch_bounds__(256) void vq_main(
    const float* __restrict__ z_e, const int* __restrict__ expert_idx,
    const float* __restrict__ cb0, const float* __restrict__ cb1,
    const float* __restrict__ cb2, const float* __restrict__ cb3,
    const float* __restrict__ csums,
    float* __restrict__ zq_out, float* __restrict__ idx_out,
    double* __restrict__ parts, unsigned char* __restrict__ flags) {
  __shared__ __align__(16) float Zs[BK * LDSTR];
  __shared__ __align__(16) float Cs[BK * LDSTR];
  __shared__ int sh_idx[TM];
  __shared__ double sh_loss[16];

  const int b  = blockIdx.y;
  const int n0 = blockIdx.x * TM;
  const int e  = expert_idx[b];
  const int K  = 256 << e;
  const float* cb = (e == 0) ? cb0 : (e == 1) ? cb1 : (e == 2) ? cb2 : cb3;
  const int cs_off = (e == 0) ? 0 : (e == 1) ? 256 : (e == 2) ? 768 : 1792;
  const float* cs = csums + cs_off;

  const int tid = threadIdx.x;
  const int tr  = tid >> 4;
  const int tc  = tid & 15;
  const int t_st = tid >> 3;
  const int q_st = tid & 7;

  const float* zbase = z_e + (size_t)(b * 1024 + n0) * 256;

  float rbv[4], rsv[4]; int rbk[4];
  #pragma unroll
  for (int i = 0; i < 4; ++i) { rbv[i] = 3.4e38f; rsv[i] = 3.4e38f; rbk[i] = 0; }

  for (int kb = 0; kb < K; kb += TN) {
    float acc[4][4];
    #pragma unroll
    for (int i = 0; i < 4; ++i)
      #pragma unroll
      for (int j = 0; j < 4; ++j) acc[i][j] = 0.f;

    for (int cc = 0; cc < 256; cc += BK) {
      __syncthreads();
      #pragma unroll
      for (int it = 0; it < 2; ++it) {
        int t = t_st + it * 32;
        float4 v = *(const float4*)(zbase + t * 256 + cc + q_st * 4);
        Zs[(q_st * 4 + 0) * LDSTR + t] = v.x;
        Zs[(q_st * 4 + 1) * LDSTR + t] = v.y;
        Zs[(q_st * 4 + 2) * LDSTR + t] = v.z;
        Zs[(q_st * 4 + 3) * LDSTR + t] = v.w;
        int k = t_st + it * 32;
        float4 w = *(const float4*)(cb + (size_t)(kb + k) * 256 + cc + q_st * 4);
        Cs[(q_st * 4 + 0) * LDSTR + k] = w.x;
        Cs[(q_st * 4 + 1) * LDSTR + k] = w.y;
        Cs[(q_st * 4 + 2) * LDSTR + k] = w.z;
        Cs[(q_st * 4 + 3) * LDSTR + k] = w.w;
      }
      __syncthreads();
      #pragma unroll
      for (int c = 0; c < BK; ++c) {
        float4 zv = *(const float4*)&Zs[c * LDSTR + tr * 4];
        float4 cv = *(const float4*)&Cs[c * LDSTR + tc * 4];
        float zr[4] = {zv.x, zv.y, zv.z, zv.w};
        float cr[4] = {cv.x, cv.y, cv.z, cv.w};
        #pragma unroll
        for (int i = 0; i < 4; ++i)
          #pragma unroll
          for (int j = 0; j < 4; ++j)
            acc[i][j] = fmaf(zr[i], cr[j], acc[i][j]);
      }
    }
    #pragma unroll
    for (int i = 0; i < 4; ++i) {
      float bv = 3.4e38f, sv = 3.4e38f; int bk = 0;
      #pragma unroll
      for (int j = 0; j < 4; ++j) {
        int k = kb + tc * 4 + j;
        float d = cs[k] - 2.0f * acc[i][j];
        if (d < bv) { sv = bv; bv = d; bk = k; }
        else         sv = fminf(sv, d);
      }
      #pragma unroll
      for (int off = 8; off >= 1; off >>= 1) {
        float ov = __shfl_xor(bv, off, 16);
        int   ok = __shfl_xor(bk, off, 16);
        float os = __shfl_xor(sv, off, 16);
        float nb; int nk;
        if (ov < bv || (ov == bv && ok < bk)) { nb = ov; nk = ok; }
        else                                  { nb = bv; nk = bk; }
        sv = fminf(fmaxf(bv, ov), fminf(sv, os));
        bv = nb; bk = nk;
      }
      float nsv = fminf(fmaxf(rbv[i], bv), fminf(rsv[i], sv));
      if (bv < rbv[i]) { rbv[i] = bv; rbk[i] = bk; }
      rsv[i] = nsv;
    }
  }

  if (tc == 0) {
    double s = 0.0;
    #pragma unroll
    for (int i = 0; i < 4; ++i) {
      int t = tr * 4 + i;
      sh_idx[t] = rbk[i];
      idx_out[b * 1024 + n0 + t] = (float)rbk[i];
      flags[b * 1024 + n0 + t] = (rsv[i] - rbv[i] < EPS_GAP) ? 1 : 0;
      s += (double)rbv[i];
    }
    sh_loss[tr] = s;
  }
  __syncthreads();
  if (tid == 0) {
    double s = 0.0;
    #pragma unroll
    for (int i = 0; i < 16; ++i) s += sh_loss[i];
    parts[blockIdx.y * 16 + blockIdx.x] = s;
  }

  const int t_zq = tid >> 6;
  const int e4   = tid & 63;
  float4* zq4 = (float4*)(zq_out + (size_t)(b * 1024 + n0) * 256);
  const float4* cb4 = (const float4*)cb;
  #pragma unroll
  for (int t0 = 0; t0 < TM; t0 += 4) {
    int t = t0 + t_zq;
    int row = sh_idx[t];
    zq4[t * 64 + e4] = cb4[row * 64 + e4];
  }
}

// ---------------- rescue: numpy-fp32-EMULATED re-rank of flagged tokens ----------------
// d32 = fl32( fl32(zsum32 + csum32_k) - fl32(2*dot64) ); argmin, ties -> lower k.
// zsum32 evaluated at 3 candidates (mid, +-1 ulp) to absorb numpy pairwise-sum
// rounding uncertainty; majority vote.
__global__ __launch_bounds__(256) void rescue_kernel(
    const float* __restrict__ z_e, const int* __restrict__ expert_idx,
    const float* __restrict__ cb0, const float* __restrict__ cb1,
    const float* __restrict__ cb2, const float* __restrict__ cb3,
    const double* __restrict__ csums64,
    const unsigned char* __restrict__ flags,
    float* __restrict__ zq_out, float* __restrict__ idx_out) {
  __shared__ float  szrow[256];
  __shared__ double szs[4];
  __shared__ float  sdv[3][256];
  __shared__ int    skv[3][256];
  __shared__ int    s_kc;
  const int tid = threadIdx.x;
  const int wid = tid >> 6, lane = tid & 63;
  const int t0 = blockIdx.x * 64;
  for (int tt = 0; tt < 64; ++tt) {
    const int t = t0 + tt;
    if (!flags[t]) continue;          // block-uniform
    const int b = t >> 10;
    const int e = expert_idx[b];
    const int K = 256 << e;
    const float* cb = (e == 0) ? cb0 : (e == 1) ? cb1 : (e == 2) ? cb2 : cb3;
    const int off = (e == 0) ? 0 : (e == 1) ? 256 : (e == 2) ? 768 : 1792;
    const double* cs64 = csums64 + off;

    __syncthreads();                  // protect shared reuse across tokens
    float zv = z_e[(size_t)t * 256 + tid];
    szrow[tid] = zv;
    double zsq = (double)zv * (double)zv;
    #pragma unroll
    for (int o = 32; o >= 1; o >>= 1) zsq += __shfl_down(zsq, o, 64);
    if (lane == 0) szs[wid] = zsq;
    __syncthreads();
    const float zs_mid = (float)(szs[0] + szs[1] + szs[2] + szs[3]);
    const unsigned zu = __float_as_uint(zs_mid);   // zsum ~ +256, safe to step
    float zs[3] = {__uint_as_float(zu - 1), zs_mid, __uint_as_float(zu + 1)};

    float bd[3] = {3.4e38f, 3.4e38f, 3.4e38f};
    int   bk[3] = {1 << 30, 1 << 30, 1 << 30};
    for (int k = tid; k < K; k += 256) {
      const float* crow = cb + (size_t)k * 256;
      double dot = 0.0;
      for (int q = 0; q < 256; q += 4) {
        dot += (double)szrow[q]     * (double)crow[q]
             + (double)szrow[q + 1] * (double)crow[q + 1]
             + (double)szrow[q + 2] * (double)crow[q + 2]
             + (double)szrow[q + 3] * (double)crow[q + 3];
      }
      const float c32 = (float)cs64[k];
      const float m2d = (float)(2.0 * dot);        // exact 2x, then fp32 round
      #pragma unroll
      for (int v = 0; v < 3; ++v) {
        float T1  = zs[v] + c32;                   // fp32 add (numpy order)
        float d32 = T1 - m2d;                      // fp32 sub
        if (d32 < bd[v]) { bd[v] = d32; bk[v] = k; }  // k asc per thread -> first-min
      }
    }
    #pragma unroll
    for (int v = 0; v < 3; ++v) { sdv[v][tid] = bd[v]; skv[v][tid] = bk[v]; }
    __syncthreads();
    for (int s = 128; s >= 1; s >>= 1) {
      if (tid < s) {
        #pragma unroll
        for (int v = 0; v < 3; ++v) {
          float od = sdv[v][tid + s]; int ok = skv[v][tid + s];
          if (od < sdv[v][tid] || (od == sdv[v][tid] && ok < skv[v][tid])) {
            sdv[v][tid] = od; skv[v][tid] = ok;
          }
        }
      }
      __syncthreads();
    }
    if (tid == 0) {
      int k0 = skv[0][0], k1 = skv[1][0], k2 = skv[2][0];
      int kc = (k0 == k2) ? k0 : k1;  // majority (all-agree/pairs), else mid
      s_kc = kc;
      idx_out[t] = (float)kc;
    }
    __syncthreads();
    const int kc = s_kc;
    if (tid < 64)
      ((float4*)(zq_out + (size_t)t * 256))[tid] =
          ((const float4*)(cb + (size_t)kc * 256))[tid];
  }
}

// ---------------- finalize: loss = 1.25*(S1+S2)/2^32 ----------------
__global__ __launch_bounds__(256) void finalize_kernel(const double* __restrict__ parts,
                                                       float* __restrict__ loss_out) {
  double s = 0.0;
  #pragma unroll
  for (int i = 0; i < 5; ++i) s += parts[threadIdx.x + 256 * i];
  #pragma unroll
  for (int off = 32; off >= 1; off >>= 1) s += __shfl_down(s, off, 64);
  __shared__ double sh[4];
  if ((threadIdx.x & 63) == 0) sh[threadIdx.x >> 6] = s;
  __syncthreads();
  if (threadIdx.x == 0)
    loss_out[0] = (float)((sh[0] + sh[1] + sh[2] + sh[3]) * (1.25 / 4294967296.0));
}

extern "C" void kernel_launch(void* const* d_in, const int* in_sizes, int n_in,
                              void* d_out, int out_size, void* d_ws, size_t ws_size,
                              hipStream_t stream) {
  const float* z_e  = (const float*)d_in[0];
  const int*   eidx = (const int*)d_in[1];
  const float* cb0  = (const float*)d_in[2];
  const float* cb1  = (const float*)d_in[3];
  const float* cb2  = (const float*)d_in[4];
  const float* cb3  = (const float*)d_in[5];

  float* zq    = (float*)d_out;                       // 64*1024*256
  float* idxf  = (float*)d_out + 16777216;            // 64*1024 as floats
  float* lossf = (float*)d_out + 16777216 + 65536;    // 1

  double*        parts_main = (double*)d_ws;          // 1024
  double*        parts_zsq  = parts_main + 1024;      // 256
  double*        csums64    = parts_zsq + 256;        // 3840
  float*         csums      = (float*)(csums64 + 3840);        // 3840
  unsigned char* flags      = (unsigned char*)(csums + 3840);  // 65536

  csum_kernel<<<960, 256, 0, stream>>>(cb0, cb1, cb2, cb3, csums, csums64);
  zsq_kernel<<<256, 256, 0, stream>>>(z_e, parts_zsq);
  dim3 grid(16, 64);
  vq_main<<<grid, 256, 0, stream>>>(z_e, eidx, cb0, cb1, cb2, cb3, csums,
                                    zq, idxf, parts_main, flags);
  rescue_kernel<<<1024, 256, 0, stream>>>(z_e, eidx, cb0, cb1, cb2, cb3,
                                          csums64, flags, zq, idxf);
  finalize_kernel<<<1, 256, 0, stream>>>(parts_main, lossf);
}

// Round 4
// 1016.491 us; speedup vs baseline: 1.3804x; 1.3804x over previous
//
#include <hip/hip_runtime.h>

// VQ-MoE R4: uniform-work decomposition. K-loop split into 256-code chunks,
// grid (16 n-tiles, 64 batches, 8 chunks); chunks beyond K/256 exit instantly.
// Per-chunk (best,k,second) partials -> combine kernel (argmin merge, flags,
// loss) -> zq gather -> numpy-fp32-emulating rescue for near-ties.
// Evidence R3: VALUBusy 50%, Occupancy 20% = expert-size load imbalance.

#define TM 64
#define TN 64
#define BK 32
#define LDSTR 68
#define EPS_GAP 2e-3f
#define NTOK 65536

// ---------------- csum: per-code ||c||^2, fp64 + fp32 views ----------------
__global__ __launch_bounds__(256) void csum_kernel(
    const float* __restrict__ cb0, const float* __restrict__ cb1,
    const float* __restrict__ cb2, const float* __restrict__ cb3,
    float* __restrict__ csums, double* __restrict__ csums64) {
  int row = blockIdx.x * 4 + (threadIdx.x >> 6);
  int lane = threadIdx.x & 63;
  const float* src; int r;
  if (row < 256)       { src = cb0; r = row; }
  else if (row < 768)  { src = cb1; r = row - 256; }
  else if (row < 1792) { src = cb2; r = row - 768; }
  else                 { src = cb3; r = row - 1792; }
  float4 v = ((const float4*)(src + r * 256))[lane];
  double s = (double)v.x*v.x + (double)v.y*v.y + (double)v.z*v.z + (double)v.w*v.w;
  #pragma unroll
  for (int off = 32; off >= 1; off >>= 1) s += __shfl_down(s, off, 64);
  if (lane == 0) { csums[row] = (float)s; csums64[row] = s; }
}

// ---------------- zsq: sum of all z^2 (fp64 partials) ----------------
__global__ __launch_bounds__(256) void zsq_kernel(const float* __restrict__ z,
                                                  double* __restrict__ parts) {
  const float4* p = (const float4*)z;
  const int n4 = 4194304;
  double s = 0.0;
  for (int i = blockIdx.x * 256 + threadIdx.x; i < n4; i += 256 * 256) {
    float4 v = p[i];
    s += (double)v.x*(double)v.x + (double)v.y*(double)v.y
       + (double)v.z*(double)v.z + (double)v.w*(double)v.w;
  }
  #pragma unroll
  for (int off = 32; off >= 1; off >>= 1) s += __shfl_down(s, off, 64);
  __shared__ double sh[4];
  if ((threadIdx.x & 63) == 0) sh[threadIdx.x >> 6] = s;
  __syncthreads();
  if (threadIdx.x == 0) parts[blockIdx.x] = sh[0] + sh[1] + sh[2] + sh[3];
}

// ---------------- partial: one 64-token x 256-code chunk ----------------
__global__ __launch_bounds__(256) void vq_partial(
    const float* __restrict__ z_e, const int* __restrict__ expert_idx,
    const float* __restrict__ cb0, const float* __restrict__ cb1,
    const float* __restrict__ cb2, const float* __restrict__ cb3,
    const float* __restrict__ csums,
    float* __restrict__ D1, int* __restrict__ K1, float* __restrict__ D2) {
  const int b  = blockIdx.y;
  const int e  = expert_idx[b];
  const int kc = blockIdx.z;
  if (kc >= (1 << e)) return;              // inert chunk (uniform exit)
  const int n0 = blockIdx.x * TM;
  const int kbase = kc * 256;

  __shared__ __align__(16) float Zs[BK * LDSTR];
  __shared__ __align__(16) float Cs[BK * LDSTR];

  const float* cb = (e == 0) ? cb0 : (e == 1) ? cb1 : (e == 2) ? cb2 : cb3;
  const int cs_off = (e == 0) ? 0 : (e == 1) ? 256 : (e == 2) ? 768 : 1792;
  const float* cs = csums + cs_off;

  const int tid = threadIdx.x;
  const int tr  = tid >> 4;
  const int tc  = tid & 15;
  const int t_st = tid >> 3;
  const int q_st = tid & 7;

  const float* zbase = z_e + (size_t)(b * 1024 + n0) * 256;

  float rbv[4], rsv[4]; int rbk[4];
  #pragma unroll
  for (int i = 0; i < 4; ++i) { rbv[i] = 3.4e38f; rsv[i] = 3.4e38f; rbk[i] = 0; }

  for (int kt = 0; kt < 4; ++kt) {
    const int kb = kbase + kt * TN;
    float acc[4][4];
    #pragma unroll
    for (int i = 0; i < 4; ++i)
      #pragma unroll
      for (int j = 0; j < 4; ++j) acc[i][j] = 0.f;

    for (int cc = 0; cc < 256; cc += BK) {
      __syncthreads();
      #pragma unroll
      for (int it = 0; it < 2; ++it) {
        int t = t_st + it * 32;
        float4 v = *(const float4*)(zbase + t * 256 + cc + q_st * 4);
        Zs[(q_st * 4 + 0) * LDSTR + t] = v.x;
        Zs[(q_st * 4 + 1) * LDSTR + t] = v.y;
        Zs[(q_st * 4 + 2) * LDSTR + t] = v.z;
        Zs[(q_st * 4 + 3) * LDSTR + t] = v.w;
        int k = t_st + it * 32;
        float4 w = *(const float4*)(cb + (size_t)(kb + k) * 256 + cc + q_st * 4);
        Cs[(q_st * 4 + 0) * LDSTR + k] = w.x;
        Cs[(q_st * 4 + 1) * LDSTR + k] = w.y;
        Cs[(q_st * 4 + 2) * LDSTR + k] = w.z;
        Cs[(q_st * 4 + 3) * LDSTR + k] = w.w;
      }
      __syncthreads();
      #pragma unroll
      for (int c = 0; c < BK; ++c) {
        float4 zv = *(const float4*)&Zs[c * LDSTR + tr * 4];
        float4 cv = *(const float4*)&Cs[c * LDSTR + tc * 4];
        float zr[4] = {zv.x, zv.y, zv.z, zv.w};
        float cr[4] = {cv.x, cv.y, cv.z, cv.w};
        #pragma unroll
        for (int i = 0; i < 4; ++i)
          #pragma unroll
          for (int j = 0; j < 4; ++j)
            acc[i][j] = fmaf(zr[i], cr[j], acc[i][j]);
      }
    }
    #pragma unroll
    for (int i = 0; i < 4; ++i) {
      float bv = 3.4e38f, sv = 3.4e38f; int bk = 0;
      #pragma unroll
      for (int j = 0; j < 4; ++j) {
        int k = kb + tc * 4 + j;
        float d = cs[k] - 2.0f * acc[i][j];
        if (d < bv) { sv = bv; bv = d; bk = k; }
        else         sv = fminf(sv, d);
      }
      #pragma unroll
      for (int off = 8; off >= 1; off >>= 1) {
        float ov = __shfl_xor(bv, off, 16);
        int   ok = __shfl_xor(bk, off, 16);
        float os = __shfl_xor(sv, off, 16);
        float nb; int nk;
        if (ov < bv || (ov == bv && ok < bk)) { nb = ov; nk = ok; }
        else                                  { nb = bv; nk = bk; }
        sv = fminf(fmaxf(bv, ov), fminf(sv, os));
        bv = nb; bk = nk;
      }
      float nsv = fminf(fmaxf(rbv[i], bv), fminf(rsv[i], sv));
      if (bv < rbv[i]) { rbv[i] = bv; rbk[i] = bk; }
      rsv[i] = nsv;
    }
  }

  if (tc == 0) {
    #pragma unroll
    for (int i = 0; i < 4; ++i) {
      int t = b * 1024 + n0 + tr * 4 + i;
      D1[kc * NTOK + t] = rbv[i];
      K1[kc * NTOK + t] = rbk[i];
      D2[kc * NTOK + t] = rsv[i];
    }
  }
}

// ---------------- combine: merge chunks -> idx, flags, loss partials ----------------
__global__ __launch_bounds__(256) void combine_kernel(
    const int* __restrict__ expert_idx,
    const float* __restrict__ D1, const int* __restrict__ K1,
    const float* __restrict__ D2,
    float* __restrict__ idx_out, unsigned char* __restrict__ flags,
    double* __restrict__ parts) {
  const int t = blockIdx.x * 256 + threadIdx.x;
  const int e = expert_idx[t >> 10];
  const int nch = 1 << e;
  float B = 3.4e38f, S = 3.4e38f; int Kb = 0;
  for (int c = 0; c < nch; ++c) {         // ascending chunk order, strict < => first-min
    float d1 = D1[c * NTOK + t];
    int   k1 = K1[c * NTOK + t];
    float d2 = D2[c * NTOK + t];
    S = fminf(fmaxf(B, d1), fminf(S, d2));
    if (d1 < B) { B = d1; Kb = k1; }
  }
  idx_out[t] = (float)Kb;
  flags[t] = (S - B < EPS_GAP) ? 1 : 0;
  // block-reduce sum of best distances for the loss
  double s = (double)B;
  #pragma unroll
  for (int off = 32; off >= 1; off >>= 1) s += __shfl_down(s, off, 64);
  __shared__ double sh[4];
  if ((threadIdx.x & 63) == 0) sh[threadIdx.x >> 6] = s;
  __syncthreads();
  if (threadIdx.x == 0) parts[blockIdx.x] = sh[0] + sh[1] + sh[2] + sh[3];
}

// ---------------- zq gather: one wave per token ----------------
__global__ __launch_bounds__(256) void zq_gather_kernel(
    const int* __restrict__ expert_idx,
    const float* __restrict__ cb0, const float* __restrict__ cb1,
    const float* __restrict__ cb2, const float* __restrict__ cb3,
    const float* __restrict__ idx_out, float* __restrict__ zq_out) {
  const int tok  = blockIdx.x * 4 + (threadIdx.x >> 6);
  const int lane = threadIdx.x & 63;
  const int e = expert_idx[tok >> 10];
  const float* cb = (e == 0) ? cb0 : (e == 1) ? cb1 : (e == 2) ? cb2 : cb3;
  const int row = (int)idx_out[tok];
  ((float4*)(zq_out + (size_t)tok * 256))[lane] =
      ((const float4*)(cb + (size_t)row * 256))[lane];
}

// ---------------- rescue: numpy-fp32-EMULATED re-rank of flagged tokens ----------------
__global__ __launch_bounds__(256) void rescue_kernel(
    const float* __restrict__ z_e, const int* __restrict__ expert_idx,
    const float* __restrict__ cb0, const float* __restrict__ cb1,
    const float* __restrict__ cb2, const float* __restrict__ cb3,
    const double* __restrict__ csums64,
    const unsigned char* __restrict__ flags,
    float* __restrict__ zq_out, float* __restrict__ idx_out) {
  __shared__ float  szrow[256];
  __shared__ double szs[4];
  __shared__ float  sdv[3][256];
  __shared__ int    skv[3][256];
  __shared__ int    s_kc;
  const int tid = threadIdx.x;
  const int wid = tid >> 6, lane = tid & 63;
  const int t0 = blockIdx.x * 64;
  for (int tt = 0; tt < 64; ++tt) {
    const int t = t0 + tt;
    if (!flags[t]) continue;          // block-uniform
    const int b = t >> 10;
    const int e = expert_idx[b];
    const int K = 256 << e;
    const float* cb = (e == 0) ? cb0 : (e == 1) ? cb1 : (e == 2) ? cb2 : cb3;
    const int off = (e == 0) ? 0 : (e == 1) ? 256 : (e == 2) ? 768 : 1792;
    const double* cs64 = csums64 + off;

    __syncthreads();
    float zv = z_e[(size_t)t * 256 + tid];
    szrow[tid] = zv;
    double zsq = (double)zv * (double)zv;
    #pragma unroll
    for (int o = 32; o >= 1; o >>= 1) zsq += __shfl_down(zsq, o, 64);
    if (lane == 0) szs[wid] = zsq;
    __syncthreads();
    const float zs_mid = (float)(szs[0] + szs[1] + szs[2] + szs[3]);
    const unsigned zu = __float_as_uint(zs_mid);
    float zs[3] = {__uint_as_float(zu - 1), zs_mid, __uint_as_float(zu + 1)};

    float bd[3] = {3.4e38f, 3.4e38f, 3.4e38f};
    int   bk[3] = {1 << 30, 1 << 30, 1 << 30};
    for (int k = tid; k < K; k += 256) {
      const float* crow = cb + (size_t)k * 256;
      double dot = 0.0;
      for (int q = 0; q < 256; q += 4) {
        dot += (double)szrow[q]     * (double)crow[q]
             + (double)szrow[q + 1] * (double)crow[q + 1]
             + (double)szrow[q + 2] * (double)crow[q + 2]
             + (double)szrow[q + 3] * (double)crow[q + 3];
      }
      const float c32 = (float)cs64[k];
      const float m2d = (float)(2.0 * dot);
      #pragma unroll
      for (int v = 0; v < 3; ++v) {
        float T1  = zs[v] + c32;
        float d32 = T1 - m2d;
        if (d32 < bd[v]) { bd[v] = d32; bk[v] = k; }
      }
    }
    #pragma unroll
    for (int v = 0; v < 3; ++v) { sdv[v][tid] = bd[v]; skv[v][tid] = bk[v]; }
    __syncthreads();
    for (int s = 128; s >= 1; s >>= 1) {
      if (tid < s) {
        #pragma unroll
        for (int v = 0; v < 3; ++v) {
          float od = sdv[v][tid + s]; int ok = skv[v][tid + s];
          if (od < sdv[v][tid] || (od == sdv[v][tid] && ok < skv[v][tid])) {
            sdv[v][tid] = od; skv[v][tid] = ok;
          }
        }
      }
      __syncthreads();
    }
    if (tid == 0) {
      int k0 = skv[0][0], k1 = skv[1][0], k2 = skv[2][0];
      int kc = (k0 == k2) ? k0 : k1;
      s_kc = kc;
      idx_out[t] = (float)kc;
    }
    __syncthreads();
    const int kc = s_kc;
    if (tid < 64)
      ((float4*)(zq_out + (size_t)t * 256))[tid] =
          ((const float4*)(cb + (size_t)kc * 256))[tid];
  }
}

// ---------------- finalize: loss = 1.25*(S1+S2)/2^32 ----------------
__global__ __launch_bounds__(256) void finalize_kernel(const double* __restrict__ parts,
                                                       float* __restrict__ loss_out) {
  double s = parts[threadIdx.x] + parts[threadIdx.x + 256];
  #pragma unroll
  for (int off = 32; off >= 1; off >>= 1) s += __shfl_down(s, off, 64);
  __shared__ double sh[4];
  if ((threadIdx.x & 63) == 0) sh[threadIdx.x >> 6] = s;
  __syncthreads();
  if (threadIdx.x == 0)
    loss_out[0] = (float)((sh[0] + sh[1] + sh[2] + sh[3]) * (1.25 / 4294967296.0));
}

extern "C" void kernel_launch(void* const* d_in, const int* in_sizes, int n_in,
                              void* d_out, int out_size, void* d_ws, size_t ws_size,
                              hipStream_t stream) {
  const float* z_e  = (const float*)d_in[0];
  const int*   eidx = (const int*)d_in[1];
  const float* cb0  = (const float*)d_in[2];
  const float* cb1  = (const float*)d_in[3];
  const float* cb2  = (const float*)d_in[4];
  const float* cb3  = (const float*)d_in[5];

  float* zq    = (float*)d_out;                       // 64*1024*256
  float* idxf  = (float*)d_out + 16777216;            // 64*1024 as floats
  float* lossf = (float*)d_out + 16777216 + 65536;    // 1

  char* w = (char*)d_ws;
  double*        parts_comb = (double*)w;              w += 256 * 8;   // combine loss
  double*        parts_zsq  = (double*)w;              w += 256 * 8;
  double*        csums64    = (double*)w;              w += 3840 * 8;
  float*         csums      = (float*)w;               w += 3840 * 4;
  unsigned char* flags      = (unsigned char*)w;       w += NTOK;
  float*         D1         = (float*)w;               w += 8 * NTOK * 4;
  int*           K1         = (int*)w;                 w += 8 * NTOK * 4;
  float*         D2         = (float*)w;               w += 8 * NTOK * 4;

  csum_kernel<<<960, 256, 0, stream>>>(cb0, cb1, cb2, cb3, csums, csums64);
  zsq_kernel<<<256, 256, 0, stream>>>(z_e, parts_zsq);
  dim3 grid(16, 64, 8);
  vq_partial<<<grid, 256, 0, stream>>>(z_e, eidx, cb0, cb1, cb2, cb3, csums,
                                       D1, K1, D2);
  combine_kernel<<<256, 256, 0, stream>>>(eidx, D1, K1, D2, idxf, flags, parts_comb);
  zq_gather_kernel<<<16384, 256, 0, stream>>>(eidx, cb0, cb1, cb2, cb3, idxf, zq);
  rescue_kernel<<<1024, 256, 0, stream>>>(z_e, eidx, cb0, cb1, cb2, cb3,
                                          csums64, flags, zq, idxf);
  finalize_kernel<<<1, 256, 0, stream>>>(parts_comb, lossf);
}

// Round 5
// 588.007 us; speedup vs baseline: 2.3863x; 1.7287x over previous
//
#include <hip/hip_runtime.h>
#include <hip/hip_bf16.h>

// VQ-MoE R5: split-bf16 MFMA main pass. z,c split into bf16 hi/lo; dot =
// z_hi*c_hi + z_lo*c_hi + z_hi*c_lo via 3 fused mfma_f32_16x16x32_bf16 per
// k-step (error ~1e-5 rms << EPS_GAP, absorbed by flag+rescue). Uniform grid
// (8 ntiles, 64 b, 16 half-chunks of 128 codes). Partials->combine->gather->
// numpy-fp32-emulating rescue unchanged from R4.

#define EPS_GAP 2e-3f
#define NTOK 65536
#define STR 40          // LDS row stride in ushorts (80 B): balanced banks for b128 frags

typedef __attribute__((ext_vector_type(8))) short bf16x8;
typedef __attribute__((ext_vector_type(4))) float f32x4;

__device__ inline unsigned short f2bf(float f) {
  __hip_bfloat16 h = __float2bfloat16(f);
  unsigned short u;
  __builtin_memcpy(&u, &h, 2);
  return u;
}
__device__ inline float bf2f(unsigned short u) {
  return __uint_as_float(((unsigned)u) << 16);
}

// ---------------- csum + codebook split: ||c||^2 (fp32+fp64) and bf16 hi/lo ----------------
__global__ __launch_bounds__(256) void csum_split_kernel(
    const float* __restrict__ cb0, const float* __restrict__ cb1,
    const float* __restrict__ cb2, const float* __restrict__ cb3,
    float* __restrict__ csums, double* __restrict__ csums64,
    unsigned short* __restrict__ cb_hi, unsigned short* __restrict__ cb_lo) {
  int row = blockIdx.x * 4 + (threadIdx.x >> 6);
  int lane = threadIdx.x & 63;
  const float* src; int r;
  if (row < 256)       { src = cb0; r = row; }
  else if (row < 768)  { src = cb1; r = row - 256; }
  else if (row < 1792) { src = cb2; r = row - 768; }
  else                 { src = cb3; r = row - 1792; }
  float4 v = ((const float4*)(src + r * 256))[lane];
  unsigned short h0 = f2bf(v.x), h1 = f2bf(v.y), h2 = f2bf(v.z), h3 = f2bf(v.w);
  unsigned short l0 = f2bf(v.x - bf2f(h0)), l1 = f2bf(v.y - bf2f(h1));
  unsigned short l2 = f2bf(v.z - bf2f(h2)), l3 = f2bf(v.w - bf2f(h3));
  *(ushort4*)(cb_hi + (size_t)row * 256 + lane * 4) = make_ushort4(h0, h1, h2, h3);
  *(ushort4*)(cb_lo + (size_t)row * 256 + lane * 4) = make_ushort4(l0, l1, l2, l3);
  double s = (double)v.x*v.x + (double)v.y*v.y + (double)v.z*v.z + (double)v.w*v.w;
  #pragma unroll
  for (int off = 32; off >= 1; off >>= 1) s += __shfl_down(s, off, 64);
  if (lane == 0) { csums[row] = (float)s; csums64[row] = s; }
}

// ---------------- zsq: sum of all z^2 (fp64 partials) ----------------
__global__ __launch_bounds__(256) void zsq_kernel(const float* __restrict__ z,
                                                  double* __restrict__ parts) {
  const float4* p = (const float4*)z;
  const int n4 = 4194304;
  double s = 0.0;
  for (int i = blockIdx.x * 256 + threadIdx.x; i < n4; i += 256 * 256) {
    float4 v = p[i];
    s += (double)v.x*(double)v.x + (double)v.y*(double)v.y
       + (double)v.z*(double)v.z + (double)v.w*(double)v.w;
  }
  #pragma unroll
  for (int off = 32; off >= 1; off >>= 1) s += __shfl_down(s, off, 64);
  __shared__ double sh[4];
  if ((threadIdx.x & 63) == 0) sh[threadIdx.x >> 6] = s;
  __syncthreads();
  if (threadIdx.x == 0) parts[blockIdx.x] = sh[0] + sh[1] + sh[2] + sh[3];
}

// ---------------- main: MFMA distances + argmin(+2nd) partials ----------------
// block 512 = 8 waves; tile M=128 tokens x N=128 codes; wave-tile 64x32.
// wave w: token-half h=w>>2, code-quarter q=w&3.
__global__ __launch_bounds__(512, 4) void vq_mfma(
    const float* __restrict__ z_e, const int* __restrict__ expert_idx,
    const unsigned short* __restrict__ cb_hi, const unsigned short* __restrict__ cb_lo,
    const float* __restrict__ csums,
    float* __restrict__ D1, int* __restrict__ K1, float* __restrict__ D2) {
  const int b  = blockIdx.y;
  const int e  = expert_idx[b];
  const int hc = blockIdx.z;
  if (hc >= (2 << e)) return;               // inert (uniform exit)
  const int cs_off = (e == 0) ? 0 : (e == 1) ? 256 : (e == 2) ? 768 : 1792;
  const int krow0  = cs_off + hc * 128;     // codebook row base for this block
  const int t0     = b * 1024 + blockIdx.x * 128;

  __shared__ ushort smem[4 * 128 * STR];    // Ah, Al, Bh, Bl  (40 KB)
  __shared__ float  sh_cs[128];
  ushort* Ah = smem;
  ushort* Al = smem + 128 * STR;
  ushort* Bh = smem + 2 * 128 * STR;
  ushort* Bl = smem + 3 * 128 * STR;

  const int tid = threadIdx.x;
  if (tid < 128) sh_cs[tid] = csums[krow0 + tid];

  const int w = tid >> 6, l = tid & 63;
  const int h = w >> 2, q = w & 3;
  const int m16 = l & 15, g = l >> 4;

  f32x4 acc[4][2];
  #pragma unroll
  for (int i = 0; i < 4; ++i)
    #pragma unroll
    for (int j = 0; j < 2; ++j) acc[i][j] = (f32x4){0.f, 0.f, 0.f, 0.f};

  for (int kp = 0; kp < 8; ++kp) {
    const int kc = kp * 32;                 // c-offset of this panel
    __syncthreads();
    // stage A: 128 tokens x 32 floats -> split bf16 hi/lo. 1024 float4 segs.
    #pragma unroll
    for (int it = 0; it < 2; ++it) {
      int idx = tid + it * 512;             // 0..1023
      int row = idx >> 3, seg = idx & 7;    // 8 float4 segs per row
      float4 v = *(const float4*)(z_e + (size_t)(t0 + row) * 256 + kc + seg * 4);
      unsigned short h0 = f2bf(v.x), h1 = f2bf(v.y), h2 = f2bf(v.z), h3 = f2bf(v.w);
      unsigned short q0 = f2bf(v.x - bf2f(h0)), q1 = f2bf(v.y - bf2f(h1));
      unsigned short q2 = f2bf(v.z - bf2f(h2)), q3 = f2bf(v.w - bf2f(h3));
      *(ushort4*)(Ah + row * STR + seg * 4) = make_ushort4(h0, h1, h2, h3);
      *(ushort4*)(Al + row * STR + seg * 4) = make_ushort4(q0, q1, q2, q3);
    }
    // stage B: 128 codes x 32 bf16 from pre-split arrays. 512 segs each.
    {
      int row = tid >> 2, seg = tid & 3;    // 4 x (8 bf16) segs per row
      const size_t go = (size_t)(krow0 + row) * 256 + kc + seg * 8;
      *(float4*)(Bh + row * STR + seg * 8) = *(const float4*)(cb_hi + go);
      *(float4*)(Bl + row * STR + seg * 8) = *(const float4*)(cb_lo + go);
    }
    __syncthreads();
    // MFMA: 24 per wave per panel, 12 ds_read_b128
    bf16x8 bh[2], bl[2];
    #pragma unroll
    for (int j = 0; j < 2; ++j) {
      int n = (q * 32 + j * 16 + m16) * STR + g * 8;
      bh[j] = *(bf16x8*)(Bh + n);
      bl[j] = *(bf16x8*)(Bl + n);
    }
    #pragma unroll
    for (int i = 0; i < 4; ++i) {
      int a = (h * 64 + i * 16 + m16) * STR + g * 8;
      bf16x8 ah = *(bf16x8*)(Ah + a);
      bf16x8 al = *(bf16x8*)(Al + a);
      #pragma unroll
      for (int j = 0; j < 2; ++j) {
        acc[i][j] = __builtin_amdgcn_mfma_f32_16x16x32_bf16(ah, bh[j], acc[i][j], 0, 0, 0);
        acc[i][j] = __builtin_amdgcn_mfma_f32_16x16x32_bf16(al, bh[j], acc[i][j], 0, 0, 0);
        acc[i][j] = __builtin_amdgcn_mfma_f32_16x16x32_bf16(ah, bl[j], acc[i][j], 0, 0, 0);
      }
    }
  }

  // ---- epilogue: per-token argmin over this block's 128 codes ----
  __syncthreads();                          // done with A/B LDS; reuse for merge
  float* mD = (float*)smem;                 // [128][4]
  int*   mK = (int*)(smem + 1024);          // byte 2048
  float* mS = (float*)(smem + 2048);        // byte 4096

  #pragma unroll
  for (int i = 0; i < 4; ++i) {
    #pragma unroll
    for (int r = 0; r < 4; ++r) {
      int k0 = q * 32 + m16;                // j=0 local code
      float d0 = sh_cs[k0]      - 2.0f * acc[i][0][r];
      float d1 = sh_cs[k0 + 16] - 2.0f * acc[i][1][r];
      float bv, sv; int bk;
      if (d0 <= d1) { bv = d0; bk = k0; sv = d1; }
      else          { bv = d1; bk = k0 + 16; sv = d0; }
      #pragma unroll
      for (int off = 8; off >= 1; off >>= 1) {
        float ov = __shfl_xor(bv, off);
        int   ok = __shfl_xor(bk, off);
        float os = __shfl_xor(sv, off);
        float nb; int nk;
        if (ov < bv || (ov == bv && ok < bk)) { nb = ov; nk = ok; }
        else                                  { nb = bv; nk = bk; }
        sv = fminf(fmaxf(bv, ov), fminf(sv, os));
        bv = nb; bk = nk;
      }
      if (m16 == 0) {
        int tloc = h * 64 + i * 16 + g * 4 + r;
        mD[tloc * 4 + q] = bv;
        mK[tloc * 4 + q] = bk;
        mS[tloc * 4 + q] = sv;
      }
    }
  }
  __syncthreads();
  if (tid < 128) {
    float B = 3.4e38f, S = 3.4e38f; int Kb = 0;
    #pragma unroll
    for (int c = 0; c < 4; ++c) {           // q ascending = codes ascending
      float d1v = mD[tid * 4 + c];
      int   k1v = mK[tid * 4 + c];
      float d2v = mS[tid * 4 + c];
      S = fminf(fmaxf(B, d1v), fminf(S, d2v));
      if (d1v < B) { B = d1v; Kb = k1v; }
    }
    int tg = t0 + tid;
    D1[hc * NTOK + tg] = B;
    K1[hc * NTOK + tg] = hc * 128 + Kb;     // absolute within codebook
    D2[hc * NTOK + tg] = S;
  }
}

// ---------------- combine: merge half-chunks -> idx, flags, loss partials ----------------
__global__ __launch_bounds__(256) void combine_kernel(
    const int* __restrict__ expert_idx,
    const float* __restrict__ D1, const int* __restrict__ K1,
    const float* __restrict__ D2,
    float* __restrict__ idx_out, unsigned char* __restrict__ flags,
    double* __restrict__ parts) {
  const int t = blockIdx.x * 256 + threadIdx.x;
  const int e = expert_idx[t >> 10];
  const int nch = 2 << e;
  float B = 3.4e38f, S = 3.4e38f; int Kb = 0;
  for (int c = 0; c < nch; ++c) {
    float d1 = D1[c * NTOK + t];
    int   k1 = K1[c * NTOK + t];
    float d2 = D2[c * NTOK + t];
    S = fminf(fmaxf(B, d1), fminf(S, d2));
    if (d1 < B) { B = d1; Kb = k1; }
  }
  idx_out[t] = (float)Kb;
  flags[t] = (S - B < EPS_GAP) ? 1 : 0;
  double s = (double)B;
  #pragma unroll
  for (int off = 32; off >= 1; off >>= 1) s += __shfl_down(s, off, 64);
  __shared__ double sh[4];
  if ((threadIdx.x & 63) == 0) sh[threadIdx.x >> 6] = s;
  __syncthreads();
  if (threadIdx.x == 0) parts[blockIdx.x] = sh[0] + sh[1] + sh[2] + sh[3];
}

// ---------------- zq gather: one wave per token ----------------
__global__ __launch_bounds__(256) void zq_gather_kernel(
    const int* __restrict__ expert_idx,
    const float* __restrict__ cb0, const float* __restrict__ cb1,
    const float* __restrict__ cb2, const float* __restrict__ cb3,
    const float* __restrict__ idx_out, float* __restrict__ zq_out) {
  const int tok  = blockIdx.x * 4 + (threadIdx.x >> 6);
  const int lane = threadIdx.x & 63;
  const int e = expert_idx[tok >> 10];
  const float* cb = (e == 0) ? cb0 : (e == 1) ? cb1 : (e == 2) ? cb2 : cb3;
  const int row = (int)idx_out[tok];
  ((float4*)(zq_out + (size_t)tok * 256))[lane] =
      ((const float4*)(cb + (size_t)row * 256))[lane];
}

// ---------------- rescue: numpy-fp32-EMULATED re-rank of flagged tokens ----------------
__global__ __launch_bounds__(256) void rescue_kernel(
    const float* __restrict__ z_e, const int* __restrict__ expert_idx,
    const float* __restrict__ cb0, const float* __restrict__ cb1,
    const float* __restrict__ cb2, const float* __restrict__ cb3,
    const double* __restrict__ csums64,
    const unsigned char* __restrict__ flags,
    float* __restrict__ zq_out, float* __restrict__ idx_out) {
  __shared__ float  szrow[256];
  __shared__ double szs[4];
  __shared__ float  sdv[3][256];
  __shared__ int    skv[3][256];
  __shared__ int    s_kc;
  const int tid = threadIdx.x;
  const int wid = tid >> 6, lane = tid & 63;
  const int t0 = blockIdx.x * 64;
  for (int tt = 0; tt < 64; ++tt) {
    const int t = t0 + tt;
    if (!flags[t]) continue;          // block-uniform
    const int b = t >> 10;
    const int e = expert_idx[b];
    const int K = 256 << e;
    const float* cb = (e == 0) ? cb0 : (e == 1) ? cb1 : (e == 2) ? cb2 : cb3;
    const int off = (e == 0) ? 0 : (e == 1) ? 256 : (e == 2) ? 768 : 1792;
    const double* cs64 = csums64 + off;

    __syncthreads();
    float zv = z_e[(size_t)t * 256 + tid];
    szrow[tid] = zv;
    double zsq = (double)zv * (double)zv;
    #pragma unroll
    for (int o = 32; o >= 1; o >>= 1) zsq += __shfl_down(zsq, o, 64);
    if (lane == 0) szs[wid] = zsq;
    __syncthreads();
    const float zs_mid = (float)(szs[0] + szs[1] + szs[2] + szs[3]);
    const unsigned zu = __float_as_uint(zs_mid);
    float zs[3] = {__uint_as_float(zu - 1), zs_mid, __uint_as_float(zu + 1)};

    float bd[3] = {3.4e38f, 3.4e38f, 3.4e38f};
    int   bk[3] = {1 << 30, 1 << 30, 1 << 30};
    for (int k = tid; k < K; k += 256) {
      const float* crow = cb + (size_t)k * 256;
      double dot = 0.0;
      for (int qq = 0; qq < 256; qq += 4) {
        dot += (double)szrow[qq]     * (double)crow[qq]
             + (double)szrow[qq + 1] * (double)crow[qq + 1]
             + (double)szrow[qq + 2] * (double)crow[qq + 2]
             + (double)szrow[qq + 3] * (double)crow[qq + 3];
      }
      const float c32 = (float)cs64[k];
      const float m2d = (float)(2.0 * dot);
      #pragma unroll
      for (int v = 0; v < 3; ++v) {
        float T1  = zs[v] + c32;
        float d32 = T1 - m2d;
        if (d32 < bd[v]) { bd[v] = d32; bk[v] = k; }
      }
    }
    #pragma unroll
    for (int v = 0; v < 3; ++v) { sdv[v][tid] = bd[v]; skv[v][tid] = bk[v]; }
    __syncthreads();
    for (int s = 128; s >= 1; s >>= 1) {
      if (tid < s) {
        #pragma unroll
        for (int v = 0; v < 3; ++v) {
          float od = sdv[v][tid + s]; int ok = skv[v][tid + s];
          if (od < sdv[v][tid] || (od == sdv[v][tid] && ok < skv[v][tid])) {
            sdv[v][tid] = od; skv[v][tid] = ok;
          }
        }
      }
      __syncthreads();
    }
    if (tid == 0) {
      int k0 = skv[0][0], k1 = skv[1][0], k2 = skv[2][0];
      int kc = (k0 == k2) ? k0 : k1;
      s_kc = kc;
      idx_out[t] = (float)kc;
    }
    __syncthreads();
    const int kc = s_kc;
    if (tid < 64)
      ((float4*)(zq_out + (size_t)t * 256))[tid] =
          ((const float4*)(cb + (size_t)kc * 256))[tid];
  }
}

// ---------------- finalize: loss = 1.25*(S1+S2)/2^32 ----------------
__global__ __launch_bounds__(256) void finalize_kernel(const double* __restrict__ parts,
                                                       float* __restrict__ loss_out) {
  double s = parts[threadIdx.x] + parts[threadIdx.x + 256];
  #pragma unroll
  for (int off = 32; off >= 1; off >>= 1) s += __shfl_down(s, off, 64);
  __shared__ double sh[4];
  if ((threadIdx.x & 63) == 0) sh[threadIdx.x >> 6] = s;
  __syncthreads();
  if (threadIdx.x == 0)
    loss_out[0] = (float)((sh[0] + sh[1] + sh[2] + sh[3]) * (1.25 / 4294967296.0));
}

extern "C" void kernel_launch(void* const* d_in, const int* in_sizes, int n_in,
                              void* d_out, int out_size, void* d_ws, size_t ws_size,
                              hipStream_t stream) {
  const float* z_e  = (const float*)d_in[0];
  const int*   eidx = (const int*)d_in[1];
  const float* cb0  = (const float*)d_in[2];
  const float* cb1  = (const float*)d_in[3];
  const float* cb2  = (const float*)d_in[4];
  const float* cb3  = (const float*)d_in[5];

  float* zq    = (float*)d_out;                       // 64*1024*256
  float* idxf  = (float*)d_out + 16777216;            // 64*1024 as floats
  float* lossf = (float*)d_out + 16777216 + 65536;    // 1

  char* wsp = (char*)d_ws;
  double*         parts_comb = (double*)wsp;           wsp += 256 * 8;
  double*         parts_zsq  = (double*)wsp;           wsp += 256 * 8;
  double*         csums64    = (double*)wsp;           wsp += 3840 * 8;
  float*          csums      = (float*)wsp;            wsp += 3840 * 4;
  unsigned char*  flags      = (unsigned char*)wsp;    wsp += NTOK;
  unsigned short* cb_hi      = (unsigned short*)wsp;   wsp += 3840 * 256 * 2;
  unsigned short* cb_lo      = (unsigned short*)wsp;   wsp += 3840 * 256 * 2;
  float*          D1         = (float*)wsp;            wsp += 16 * NTOK * 4;
  int*            K1         = (int*)wsp;              wsp += 16 * NTOK * 4;
  float*          D2         = (float*)wsp;            wsp += 16 * NTOK * 4;

  csum_split_kernel<<<960, 256, 0, stream>>>(cb0, cb1, cb2, cb3,
                                             csums, csums64, cb_hi, cb_lo);
  zsq_kernel<<<256, 256, 0, stream>>>(z_e, parts_zsq);
  dim3 grid(8, 64, 16);
  vq_mfma<<<grid, 512, 0, stream>>>(z_e, eidx, cb_hi, cb_lo, csums, D1, K1, D2);
  combine_kernel<<<256, 256, 0, stream>>>(eidx, D1, K1, D2, idxf, flags, parts_comb);
  zq_gather_kernel<<<16384, 256, 0, stream>>>(eidx, cb0, cb1, cb2, cb3, idxf, zq);
  rescue_kernel<<<1024, 256, 0, stream>>>(z_e, eidx, cb0, cb1, cb2, cb3,
                                          csums64, flags, zq, idxf);
  finalize_kernel<<<1, 256, 0, stream>>>(parts_comb, lossf);
}

// Round 6
// 481.615 us; speedup vs baseline: 2.9134x; 1.2209x over previous
//
#include <hip/hip_runtime.h>
#include <hip/hip_bf16.h>

// VQ-MoE R6: same split-bf16 MFMA main pass as R5. Rescue restructured:
// flags -> compacted worklist -> one block per flagged token (was: 64-token
// serial sweep per block -> 238us straggler at 5% occupancy).

#define EPS_GAP 2e-3f
#define NTOK 65536

#define STR 40          // LDS row stride in ushorts (80 B)

typedef __attribute__((ext_vector_type(8))) short bf16x8;
typedef __attribute__((ext_vector_type(4))) float f32x4;

__device__ inline unsigned short f2bf(float f) {
  __hip_bfloat16 h = __float2bfloat16(f);
  unsigned short u;
  __builtin_memcpy(&u, &h, 2);
  return u;
}
__device__ inline float bf2f(unsigned short u) {
  return __uint_as_float(((unsigned)u) << 16);
}

// ---------------- csum + codebook split (+ zero worklist counter) ----------------
__global__ __launch_bounds__(256) void csum_split_kernel(
    const float* __restrict__ cb0, const float* __restrict__ cb1,
    const float* __restrict__ cb2, const float* __restrict__ cb3,
    float* __restrict__ csums, double* __restrict__ csums64,
    unsigned short* __restrict__ cb_hi, unsigned short* __restrict__ cb_lo,
    int* __restrict__ wl_cnt) {
  if (blockIdx.x == 0 && threadIdx.x == 0) wl_cnt[0] = 0;  // stream-ordered init
  int row = blockIdx.x * 4 + (threadIdx.x >> 6);
  int lane = threadIdx.x & 63;
  const float* src; int r;
  if (row < 256)       { src = cb0; r = row; }
  else if (row < 768)  { src = cb1; r = row - 256; }
  else if (row < 1792) { src = cb2; r = row - 768; }
  else                 { src = cb3; r = row - 1792; }
  float4 v = ((const float4*)(src + r * 256))[lane];
  unsigned short h0 = f2bf(v.x), h1 = f2bf(v.y), h2 = f2bf(v.z), h3 = f2bf(v.w);
  unsigned short l0 = f2bf(v.x - bf2f(h0)), l1 = f2bf(v.y - bf2f(h1));
  unsigned short l2 = f2bf(v.z - bf2f(h2)), l3 = f2bf(v.w - bf2f(h3));
  *(ushort4*)(cb_hi + (size_t)row * 256 + lane * 4) = make_ushort4(h0, h1, h2, h3);
  *(ushort4*)(cb_lo + (size_t)row * 256 + lane * 4) = make_ushort4(l0, l1, l2, l3);
  double s = (double)v.x*v.x + (double)v.y*v.y + (double)v.z*v.z + (double)v.w*v.w;
  #pragma unroll
  for (int off = 32; off >= 1; off >>= 1) s += __shfl_down(s, off, 64);
  if (lane == 0) { csums[row] = (float)s; csums64[row] = s; }
}

// ---------------- zsq: sum of all z^2 (fp64 partials) ----------------
__global__ __launch_bounds__(256) void zsq_kernel(const float* __restrict__ z,
                                                  double* __restrict__ parts) {
  const float4* p = (const float4*)z;
  const int n4 = 4194304;
  double s = 0.0;
  for (int i = blockIdx.x * 256 + threadIdx.x; i < n4; i += 256 * 256) {
    float4 v = p[i];
    s += (double)v.x*(double)v.x + (double)v.y*(double)v.y
       + (double)v.z*(double)v.z + (double)v.w*(double)v.w;
  }
  #pragma unroll
  for (int off = 32; off >= 1; off >>= 1) s += __shfl_down(s, off, 64);
  __shared__ double sh[4];
  if ((threadIdx.x & 63) == 0) sh[threadIdx.x >> 6] = s;
  __syncthreads();
  if (threadIdx.x == 0) parts[blockIdx.x] = sh[0] + sh[1] + sh[2] + sh[3];
}

// ---------------- main: MFMA distances + argmin(+2nd) partials ----------------
__global__ __launch_bounds__(512, 4) void vq_mfma(
    const float* __restrict__ z_e, const int* __restrict__ expert_idx,
    const unsigned short* __restrict__ cb_hi, const unsigned short* __restrict__ cb_lo,
    const float* __restrict__ csums,
    float* __restrict__ D1, int* __restrict__ K1, float* __restrict__ D2) {
  const int b  = blockIdx.y;
  const int e  = expert_idx[b];
  const int hc = blockIdx.z;
  if (hc >= (2 << e)) return;               // inert (uniform exit)
  const int cs_off = (e == 0) ? 0 : (e == 1) ? 256 : (e == 2) ? 768 : 1792;
  const int krow0  = cs_off + hc * 128;
  const int t0     = b * 1024 + blockIdx.x * 128;

  __shared__ ushort smem[4 * 128 * STR];    // Ah, Al, Bh, Bl  (40 KB)
  __shared__ float  sh_cs[128];
  ushort* Ah = smem;
  ushort* Al = smem + 128 * STR;
  ushort* Bh = smem + 2 * 128 * STR;
  ushort* Bl = smem + 3 * 128 * STR;

  const int tid = threadIdx.x;
  if (tid < 128) sh_cs[tid] = csums[krow0 + tid];

  const int w = tid >> 6, l = tid & 63;
  const int h = w >> 2, q = w & 3;
  const int m16 = l & 15, g = l >> 4;

  f32x4 acc[4][2];
  #pragma unroll
  for (int i = 0; i < 4; ++i)
    #pragma unroll
    for (int j = 0; j < 2; ++j) acc[i][j] = (f32x4){0.f, 0.f, 0.f, 0.f};

  for (int kp = 0; kp < 8; ++kp) {
    const int kc = kp * 32;
    __syncthreads();
    #pragma unroll
    for (int it = 0; it < 2; ++it) {
      int idx = tid + it * 512;
      int row = idx >> 3, seg = idx & 7;
      float4 v = *(const float4*)(z_e + (size_t)(t0 + row) * 256 + kc + seg * 4);
      unsigned short h0 = f2bf(v.x), h1 = f2bf(v.y), h2 = f2bf(v.z), h3 = f2bf(v.w);
      unsigned short q0 = f2bf(v.x - bf2f(h0)), q1 = f2bf(v.y - bf2f(h1));
      unsigned short q2 = f2bf(v.z - bf2f(h2)), q3 = f2bf(v.w - bf2f(h3));
      *(ushort4*)(Ah + row * STR + seg * 4) = make_ushort4(h0, h1, h2, h3);
      *(ushort4*)(Al + row * STR + seg * 4) = make_ushort4(q0, q1, q2, q3);
    }
    {
      int row = tid >> 2, seg = tid & 3;
      const size_t go = (size_t)(krow0 + row) * 256 + kc + seg * 8;
      *(float4*)(Bh + row * STR + seg * 8) = *(const float4*)(cb_hi + go);
      *(float4*)(Bl + row * STR + seg * 8) = *(const float4*)(cb_lo + go);
    }
    __syncthreads();
    bf16x8 bh[2], bl[2];
    #pragma unroll
    for (int j = 0; j < 2; ++j) {
      int n = (q * 32 + j * 16 + m16) * STR + g * 8;
      bh[j] = *(bf16x8*)(Bh + n);
      bl[j] = *(bf16x8*)(Bl + n);
    }
    #pragma unroll
    for (int i = 0; i < 4; ++i) {
      int a = (h * 64 + i * 16 + m16) * STR + g * 8;
      bf16x8 ah = *(bf16x8*)(Ah + a);
      bf16x8 al = *(bf16x8*)(Al + a);
      #pragma unroll
      for (int j = 0; j < 2; ++j) {
        acc[i][j] = __builtin_amdgcn_mfma_f32_16x16x32_bf16(ah, bh[j], acc[i][j], 0, 0, 0);
        acc[i][j] = __builtin_amdgcn_mfma_f32_16x16x32_bf16(al, bh[j], acc[i][j], 0, 0, 0);
        acc[i][j] = __builtin_amdgcn_mfma_f32_16x16x32_bf16(ah, bl[j], acc[i][j], 0, 0, 0);
      }
    }
  }

  __syncthreads();
  float* mD = (float*)smem;
  int*   mK = (int*)(smem + 1024);
  float* mS = (float*)(smem + 2048);

  #pragma unroll
  for (int i = 0; i < 4; ++i) {
    #pragma unroll
    for (int r = 0; r < 4; ++r) {
      int k0 = q * 32 + m16;
      float d0 = sh_cs[k0]      - 2.0f * acc[i][0][r];
      float d1 = sh_cs[k0 + 16] - 2.0f * acc[i][1][r];
      float bv, sv; int bk;
      if (d0 <= d1) { bv = d0; bk = k0; sv = d1; }
      else          { bv = d1; bk = k0 + 16; sv = d0; }
      #pragma unroll
      for (int off = 8; off >= 1; off >>= 1) {
        float ov = __shfl_xor(bv, off);
        int   ok = __shfl_xor(bk, off);
        float os = __shfl_xor(sv, off);
        float nb; int nk;
        if (ov < bv || (ov == bv && ok < bk)) { nb = ov; nk = ok; }
        else                                  { nb = bv; nk = bk; }
        sv = fminf(fmaxf(bv, ov), fminf(sv, os));
        bv = nb; bk = nk;
      }
      if (m16 == 0) {
        int tloc = h * 64 + i * 16 + g * 4 + r;
        mD[tloc * 4 + q] = bv;
        mK[tloc * 4 + q] = bk;
        mS[tloc * 4 + q] = sv;
      }
    }
  }
  __syncthreads();
  if (tid < 128) {
    float B = 3.4e38f, S = 3.4e38f; int Kb = 0;
    #pragma unroll
    for (int c = 0; c < 4; ++c) {
      float d1v = mD[tid * 4 + c];
      int   k1v = mK[tid * 4 + c];
      float d2v = mS[tid * 4 + c];
      S = fminf(fmaxf(B, d1v), fminf(S, d2v));
      if (d1v < B) { B = d1v; Kb = k1v; }
    }
    int tg = t0 + tid;
    D1[hc * NTOK + tg] = B;
    K1[hc * NTOK + tg] = hc * 128 + Kb;
    D2[hc * NTOK + tg] = S;
  }
}

// ---------------- combine: merge half-chunks -> idx, flags, loss partials ----------------
__global__ __launch_bounds__(256) void combine_kernel(
    const int* __restrict__ expert_idx,
    const float* __restrict__ D1, const int* __restrict__ K1,
    const float* __restrict__ D2,
    float* __restrict__ idx_out, unsigned char* __restrict__ flags,
    double* __restrict__ parts) {
  const int t = blockIdx.x * 256 + threadIdx.x;
  const int e = expert_idx[t >> 10];
  const int nch = 2 << e;
  float B = 3.4e38f, S = 3.4e38f; int Kb = 0;
  for (int c = 0; c < nch; ++c) {
    float d1 = D1[c * NTOK + t];
    int   k1 = K1[c * NTOK + t];
    float d2 = D2[c * NTOK + t];
    S = fminf(fmaxf(B, d1), fminf(S, d2));
    if (d1 < B) { B = d1; Kb = k1; }
  }
  idx_out[t] = (float)Kb;
  flags[t] = (S - B < EPS_GAP) ? 1 : 0;
  double s = (double)B;
  #pragma unroll
  for (int off = 32; off >= 1; off >>= 1) s += __shfl_down(s, off, 64);
  __shared__ double sh[4];
  if ((threadIdx.x & 63) == 0) sh[threadIdx.x >> 6] = s;
  __syncthreads();
  if (threadIdx.x == 0) parts[blockIdx.x] = sh[0] + sh[1] + sh[2] + sh[3];
}

// ---------------- compact: flagged token ids -> worklist ----------------
__global__ __launch_bounds__(256) void compact_kernel(
    const unsigned char* __restrict__ flags,
    int* __restrict__ wl, int* __restrict__ wl_cnt) {
  const int t = blockIdx.x * 256 + threadIdx.x;
  if (flags[t]) {
    int p = atomicAdd(wl_cnt, 1);
    wl[p] = t;
  }
}

// ---------------- zq gather: one wave per token ----------------
__global__ __launch_bounds__(256) void zq_gather_kernel(
    const int* __restrict__ expert_idx,
    const float* __restrict__ cb0, const float* __restrict__ cb1,
    const float* __restrict__ cb2, const float* __restrict__ cb3,
    const float* __restrict__ idx_out, float* __restrict__ zq_out) {
  const int tok  = blockIdx.x * 4 + (threadIdx.x >> 6);
  const int lane = threadIdx.x & 63;
  const int e = expert_idx[tok >> 10];
  const float* cb = (e == 0) ? cb0 : (e == 1) ? cb1 : (e == 2) ? cb2 : cb3;
  const int row = (int)idx_out[tok];
  ((float4*)(zq_out + (size_t)tok * 256))[lane] =
      ((const float4*)(cb + (size_t)row * 256))[lane];
}

// ---------------- rescue: numpy-fp32-EMULATED re-rank, one block per flagged token ----------------
__global__ __launch_bounds__(256) void rescue_kernel(
    const float* __restrict__ z_e, const int* __restrict__ expert_idx,
    const float* __restrict__ cb0, const float* __restrict__ cb1,
    const float* __restrict__ cb2, const float* __restrict__ cb3,
    const double* __restrict__ csums64,
    const int* __restrict__ wl, const int* __restrict__ wl_cnt,
    float* __restrict__ zq_out, float* __restrict__ idx_out) {
  __shared__ float  szrow[256];
  __shared__ double szs[4];
  __shared__ float  sdv[3][256];
  __shared__ int    skv[3][256];
  __shared__ int    s_kc;
  const int tid = threadIdx.x;
  const int wid = tid >> 6, lane = tid & 63;
  const int n = wl_cnt[0];
  for (int it = blockIdx.x; it < n; it += gridDim.x) {
    const int t = wl[it];
    const int b = t >> 10;
    const int e = expert_idx[b];
    const int K = 256 << e;
    const float* cb = (e == 0) ? cb0 : (e == 1) ? cb1 : (e == 2) ? cb2 : cb3;
    const int off = (e == 0) ? 0 : (e == 1) ? 256 : (e == 2) ? 768 : 1792;
    const double* cs64 = csums64 + off;

    __syncthreads();                       // protect shared reuse across iterations
    float zv = z_e[(size_t)t * 256 + tid];
    szrow[tid] = zv;
    double zsq = (double)zv * (double)zv;
    #pragma unroll
    for (int o = 32; o >= 1; o >>= 1) zsq += __shfl_down(zsq, o, 64);
    if (lane == 0) szs[wid] = zsq;
    __syncthreads();
    const float zs_mid = (float)(szs[0] + szs[1] + szs[2] + szs[3]);
    const unsigned zu = __float_as_uint(zs_mid);
    float zs[3] = {__uint_as_float(zu - 1), zs_mid, __uint_as_float(zu + 1)};

    float bd[3] = {3.4e38f, 3.4e38f, 3.4e38f};
    int   bk[3] = {1 << 30, 1 << 30, 1 << 30};
    const float4* z4 = (const float4*)szrow;
    for (int k = tid; k < K; k += 256) {
      const float4* c4 = (const float4*)(cb + (size_t)k * 256);
      double d0 = 0.0, d1v = 0.0, d2v = 0.0, d3 = 0.0;   // 4 indep chains
      for (int qq = 0; qq < 64; qq += 4) {
        float4 a0 = z4[qq],     c0 = c4[qq];
        float4 a1 = z4[qq + 1], c1 = c4[qq + 1];
        float4 a2 = z4[qq + 2], c2 = c4[qq + 2];
        float4 a3 = z4[qq + 3], c3 = c4[qq + 3];
        d0 += (double)a0.x*c0.x + (double)a0.y*c0.y + (double)a0.z*c0.z + (double)a0.w*c0.w;
        d1v+= (double)a1.x*c1.x + (double)a1.y*c1.y + (double)a1.z*c1.z + (double)a1.w*c1.w;
        d2v+= (double)a2.x*c2.x + (double)a2.y*c2.y + (double)a2.z*c2.z + (double)a2.w*c2.w;
        d3 += (double)a3.x*c3.x + (double)a3.y*c3.y + (double)a3.z*c3.z + (double)a3.w*c3.w;
      }
      double dot = (d0 + d1v) + (d2v + d3);
      const float c32 = (float)cs64[k];
      const float m2d = (float)(2.0 * dot);
      #pragma unroll
      for (int v = 0; v < 3; ++v) {
        float T1  = zs[v] + c32;           // numpy order: (zsum+csum) - 2dot
        float d32 = T1 - m2d;
        if (d32 < bd[v]) { bd[v] = d32; bk[v] = k; }
      }
    }
    #pragma unroll
    for (int v = 0; v < 3; ++v) { sdv[v][tid] = bd[v]; skv[v][tid] = bk[v]; }
    __syncthreads();
    for (int s = 128; s >= 1; s >>= 1) {
      if (tid < s) {
        #pragma unroll
        for (int v = 0; v < 3; ++v) {
          float od = sdv[v][tid + s]; int ok = skv[v][tid + s];
          if (od < sdv[v][tid] || (od == sdv[v][tid] && ok < skv[v][tid])) {
            sdv[v][tid] = od; skv[v][tid] = ok;
          }
        }
      }
      __syncthreads();
    }
    if (tid == 0) {
      int k0 = skv[0][0], k1 = skv[1][0], k2 = skv[2][0];
      int kc = (k0 == k2) ? k0 : k1;       // majority vote over zsum ulp variants
      s_kc = kc;
      idx_out[t] = (float)kc;
    }
    __syncthreads();
    const int kc = s_kc;
    if (tid < 64)
      ((float4*)(zq_out + (size_t)t * 256))[tid] =
          ((const float4*)(cb + (size_t)kc * 256))[tid];
  }
}

// ---------------- finalize: loss = 1.25*(S1+S2)/2^32 ----------------
__global__ __launch_bounds__(256) void finalize_kernel(const double* __restrict__ parts,
                                                       float* __restrict__ loss_out) {
  double s = parts[threadIdx.x] + parts[threadIdx.x + 256];
  #pragma unroll
  for (int off = 32; off >= 1; off >>= 1) s += __shfl_down(s, off, 64);
  __shared__ double sh[4];
  if ((threadIdx.x & 63) == 0) sh[threadIdx.x >> 6] = s;
  __syncthreads();
  if (threadIdx.x == 0)
    loss_out[0] = (float)((sh[0] + sh[1] + sh[2] + sh[3]) * (1.25 / 4294967296.0));
}

extern "C" void kernel_launch(void* const* d_in, const int* in_sizes, int n_in,
                              void* d_out, int out_size, void* d_ws, size_t ws_size,
                              hipStream_t stream) {
  const float* z_e  = (const float*)d_in[0];
  const int*   eidx = (const int*)d_in[1];
  const float* cb0  = (const float*)d_in[2];
  const float* cb1  = (const float*)d_in[3];
  const float* cb2  = (const float*)d_in[4];
  const float* cb3  = (const float*)d_in[5];

  float* zq    = (float*)d_out;                       // 64*1024*256
  float* idxf  = (float*)d_out + 16777216;            // 64*1024 as floats
  float* lossf = (float*)d_out + 16777216 + 65536;    // 1

  char* wsp = (char*)d_ws;
  double*         parts_comb = (double*)wsp;           wsp += 256 * 8;
  double*         parts_zsq  = (double*)wsp;           wsp += 256 * 8;
  double*         csums64    = (double*)wsp;           wsp += 3840 * 8;
  float*          csums      = (float*)wsp;            wsp += 3840 * 4;
  int*            wl_cnt     = (int*)wsp;              wsp += 16;
  unsigned char*  flags      = (unsigned char*)wsp;    wsp += NTOK;
  int*            wl         = (int*)wsp;              wsp += NTOK * 4;
  unsigned short* cb_hi      = (unsigned short*)wsp;   wsp += 3840 * 256 * 2;
  unsigned short* cb_lo      = (unsigned short*)wsp;   wsp += 3840 * 256 * 2;
  float*          D1         = (float*)wsp;            wsp += 16 * NTOK * 4;
  int*            K1         = (int*)wsp;              wsp += 16 * NTOK * 4;
  float*          D2         = (float*)wsp;            wsp += 16 * NTOK * 4;

  csum_split_kernel<<<960, 256, 0, stream>>>(cb0, cb1, cb2, cb3,
                                             csums, csums64, cb_hi, cb_lo, wl_cnt);
  zsq_kernel<<<256, 256, 0, stream>>>(z_e, parts_zsq);
  dim3 grid(8, 64, 16);
  vq_mfma<<<grid, 512, 0, stream>>>(z_e, eidx, cb_hi, cb_lo, csums, D1, K1, D2);
  combine_kernel<<<256, 256, 0, stream>>>(eidx, D1, K1, D2, idxf, flags, parts_comb);
  compact_kernel<<<256, 256, 0, stream>>>(flags, wl, wl_cnt);
  zq_gather_kernel<<<16384, 256, 0, stream>>>(eidx, cb0, cb1, cb2, cb3, idxf, zq);
  rescue_kernel<<<2048, 256, 0, stream>>>(z_e, eidx, cb0, cb1, cb2, cb3,
                                          csums64, wl, wl_cnt, zq, idxf);
  finalize_kernel<<<1, 256, 0, stream>>>(parts_comb, lossf);
}